// Round 12
// baseline (29.483 us; speedup 1.0000x reference)
//
#include <hip/hip_runtime.h>
#include <hip/hip_bf16.h>

typedef __bf16 bf16_t;
typedef __bf16 bf16x4 __attribute__((ext_vector_type(4)));
typedef __bf16 bf16x8 __attribute__((ext_vector_type(8)));
typedef float  f32x4  __attribute__((ext_vector_type(4)));

typedef __attribute__((address_space(1))) const void  gvoid_t;
typedef __attribute__((address_space(3))) void        lvoid_t;

static constexpr int Mtot = 4096;   // B*S
static constexpr int Ntot = 1024;   // H*A
static constexpr int Ktot = 1024;   // F

// out[b,s,h,a] = sum_f value_input[b,s,f] * v_w[h,f,a]
// (reference softmax over q integrates to exactly 1 in the final q-contraction)

// ============================================================================
// Prepass (W only, 6 MB): Wt = bf16 transpose of W -> [n=h*64+a][k]
// ============================================================================
__global__ __launch_bounds__(256)
void prepass_w_kernel(const float* __restrict__ W, bf16_t* __restrict__ Wt)
{
    __shared__ float wtile[64][65];
    const int wb = blockIdx.x, t = threadIdx.x;
    const int head = wb >> 4;
    const int k0 = (wb & 15) * 64;
    const float* wsrc = W + (size_t)head * (Ktot * 64) + (size_t)k0 * 64;
#pragma unroll
    for (int i = 0; i < 4; ++i) {
        const int idx = i * 256 + t;
        const int kr = idx >> 4, a4 = (idx & 15) * 4;
        const f32x4 v = *(const f32x4*)(wsrc + (size_t)kr * 64 + a4);
        wtile[kr][a4 + 0] = v[0]; wtile[kr][a4 + 1] = v[1];
        wtile[kr][a4 + 2] = v[2]; wtile[kr][a4 + 3] = v[3];
    }
    __syncthreads();
#pragma unroll
    for (int i = 0; i < 4; ++i) {
        const int idx = i * 256 + t;
        const int ar = idx >> 4, kc = (idx & 15) * 4;
        bf16x4 p = {(bf16_t)wtile[kc + 0][ar], (bf16_t)wtile[kc + 1][ar],
                    (bf16_t)wtile[kc + 2][ar], (bf16_t)wtile[kc + 3][ar]};
        *(bf16x4*)(Wt + (size_t)(head * 64 + ar) * Ktot + k0 + kc) = p;
    }
}

// ============================================================================
// GEMM with fused A-conversion (R4 structure + T14 staging split).
// BM=64 BN=128 BK=64, 4 waves (2x2, wave-tile 32x64), grid 512 = 2 blocks/CU.
// A: fp32 global loads issued BEFORE compute; cvt + swizzled ds_write_b128
//    AFTER compute (hidden under MFMA + B staging). LDS stays bf16-sized.
// B: global_load_lds from Wt (rule-#21 XOR swizzle: linear dest, permuted src).
// All LDS ops conflict-free under the XOR pattern (bank = f(slot) only,
// 8 lanes per 16B slot-group -> even 8-cycle b128).
// ============================================================================
__global__ __launch_bounds__(256, 2)
void gemm_fusedA_kernel(const float* __restrict__ A, const bf16_t* __restrict__ Bt,
                        float* __restrict__ C)
{
    __shared__ bf16_t As[2][64 * 64];    // [row][64k] bf16, swizzled content
    __shared__ bf16_t Bs[2][128 * 64];

    const int t = threadIdx.x, lane = t & 63, wave = t >> 6;
    const int wm = wave & 1, wn = wave >> 1;

    // XCD swizzle: 512 wgs; XCD x owns 8 M-panels x all 8 N
    // (A fp32 slice 2MB + Wt 2MB -> L2-resident per XCD)
    const int g = (blockIdx.x & 7) * 64 + (blockIdx.x >> 3);
    const int by = g >> 3, bx = g & 7;
    const int bm = by * 64, bn = bx * 128;

    const int lrow = lane & 15;
    const int lq   = lane >> 4;

    f32x4 acc[2][4];
#pragma unroll
    for (int mf = 0; mf < 2; ++mf)
#pragma unroll
        for (int nf = 0; nf < 4; ++nf) {
            f32x4 z = {0.f, 0.f, 0.f, 0.f};
            acc[mf][nf] = z;
        }

    // ---- A reg-staging coords: 2 chunks/thread, mirrors gload_lds layout ----
    // chunk = (wave*2+j)*64 + lane ; row = chunk>>3 ; kb = ((chunk&7)^(row&7))*8
    int aRow[2], aKb[2];
#pragma unroll
    for (int j = 0; j < 2; ++j) {
        const int chunk = (wave * 2 + j) * 64 + lane;
        aRow[j] = chunk >> 3;
        aKb[j]  = ((chunk & 7) ^ (aRow[j] & 7)) * 8;
    }
    f32x4 aReg[2][2];

    auto LOADA = [&](int k0) {
#pragma unroll
        for (int j = 0; j < 2; ++j) {
            const float* ap = A + (size_t)(bm + aRow[j]) * Ktot + k0 + aKb[j];
            aReg[j][0] = *(const f32x4*)(ap);
            aReg[j][1] = *(const f32x4*)(ap + 4);
        }
    };
    auto WRITEA = [&](int buf) {
#pragma unroll
        for (int j = 0; j < 2; ++j) {
            bf16x8 v = {(bf16_t)aReg[j][0][0], (bf16_t)aReg[j][0][1],
                        (bf16_t)aReg[j][0][2], (bf16_t)aReg[j][0][3],
                        (bf16_t)aReg[j][1][0], (bf16_t)aReg[j][1][1],
                        (bf16_t)aReg[j][1][2], (bf16_t)aReg[j][1][3]};
            *(bf16x8*)&As[buf][(wave * 2 + j) * 512 + lane * 8] = v;
        }
    };

    // ---- B staging: 4 gload_lds/thread (rule-#21: linear dest, swizzled src) --
    auto STAGEB = [&](int buf, int k0) {
#pragma unroll
        for (int j = 0; j < 4; ++j) {
            const int chunk = (wave * 4 + j) * 64 + lane;
            const int row = chunk >> 3;
            const int kb  = ((chunk & 7) ^ (row & 7)) * 8;
            const bf16_t* gp = Bt + (size_t)(bn + row) * Ktot + k0 + kb;
            __builtin_amdgcn_global_load_lds((gvoid_t*)gp,
                (lvoid_t*)&Bs[buf][(wave * 4 + j) * 512], 16, 0, 0);
        }
    };

    auto COMPUTE = [&](int cur) {
#pragma unroll
        for (int kk = 0; kk < 2; ++kk) {
            const int c16 = kk * 4 + lq;
            bf16x8 af[2], bfr[4];
#pragma unroll
            for (int mf = 0; mf < 2; ++mf) {
                const int R = wm * 32 + mf * 16 + lrow;
                af[mf] = *(const bf16x8*)&As[cur][R * 64 + ((c16 ^ (R & 7)) << 3)];
            }
#pragma unroll
            for (int nf = 0; nf < 4; ++nf) {
                const int R = wn * 64 + nf * 16 + lrow;
                bfr[nf] = *(const bf16x8*)&Bs[cur][R * 64 + ((c16 ^ (R & 7)) << 3)];
            }
            __builtin_amdgcn_s_setprio(1);
#pragma unroll
            for (int mf = 0; mf < 2; ++mf)
#pragma unroll
                for (int nf = 0; nf < 4; ++nf)
                    acc[mf][nf] = __builtin_amdgcn_mfma_f32_16x16x32_bf16(
                        af[mf], bfr[nf], acc[mf][nf], 0, 0, 0);
            __builtin_amdgcn_s_setprio(0);
        }
    };

    // prologue: stage tile 0 (A regs -> LDS, B gload_lds)
    LOADA(0);
    WRITEA(0);
    STAGEB(0, 0);
    __syncthreads();

    constexpr int NT = Ktot / 64;   // 16
    for (int tI = 0; tI < NT; ++tI) {
        const int cur = tI & 1;
        if (tI + 1 < NT) {
            LOADA((tI + 1) * 64);          // issue fp32 loads early (T14)
            STAGEB(cur ^ 1, (tI + 1) * 64);
        }
        COMPUTE(cur);
        if (tI + 1 < NT) WRITEA(cur ^ 1);  // cvt + ds_write after compute
        __syncthreads();                   // drains vmcnt + lgkm for next tile
    }

    // epilogue: C/D layout col = lane&15, row = (lane>>4)*4 + i
#pragma unroll
    for (int mf = 0; mf < 2; ++mf) {
        const int row0 = bm + wm * 32 + mf * 16 + (lq << 2);
#pragma unroll
        for (int nf = 0; nf < 4; ++nf) {
            const int col = bn + wn * 64 + nf * 16 + lrow;
#pragma unroll
            for (int i = 0; i < 4; ++i)
                C[(size_t)(row0 + i) * Ntot + col] = acc[mf][nf][i];
        }
    }
}

// ============================================================================
// Fallback (ws too small): round-2 fused kernel (proven correct, ~33 us)
// ============================================================================
static constexpr int FBM = 128, FBN = 128, FBK = 64, FBKP = 72;

__global__ __launch_bounds__(512, 2)
void vproj_fused_kernel(const float* __restrict__ A, const float* __restrict__ W,
                        float* __restrict__ C)
{
    __shared__ bf16_t As[2][FBM][FBKP];
    __shared__ bf16_t Bs[2][FBN][FBKP];

    const int t = threadIdx.x, lane = t & 63, wave = t >> 6;
    const int wm = wave >> 2, wn = wave & 3;
    const int tile = (blockIdx.x & 7) * 32 + (blockIdx.x >> 3);
    const int bm = (tile >> 3) * FBM, bn = (tile & 7) * FBN;

    const int bhead = t >> 8, brem = t & 255;
    const int bkq = brem >> 4, baq = brem & 15;
    const float* const wbase = W + ((size_t)((bn >> 6) + bhead)) * (Ktot * 64)
                                 + (size_t)(bkq * 4) * 64 + baq * 4;
    f32x4 avreg[4], bvreg[4];

    auto load_tile = [&](int k0) {
#pragma unroll
        for (int r = 0; r < 4; ++r) {
            const int idx = r * 512 + t;
            avreg[r] = *(const f32x4*)(A + (size_t)(bm + (idx >> 4)) * Ktot + k0 + (idx & 15) * 4);
        }
        const float* wp = wbase + (size_t)k0 * 64;
#pragma unroll
        for (int r = 0; r < 4; ++r) bvreg[r] = *(const f32x4*)(wp + r * 64);
    };
    auto store_tile = [&](int buf) {
#pragma unroll
        for (int r = 0; r < 4; ++r) {
            const int idx = r * 512 + t;
            bf16_t* dst = &As[buf][idx >> 4][(idx & 15) * 4];
            dst[0] = (bf16_t)avreg[r][0]; dst[1] = (bf16_t)avreg[r][1];
            dst[2] = (bf16_t)avreg[r][2]; dst[3] = (bf16_t)avreg[r][3];
        }
#pragma unroll
        for (int j = 0; j < 4; ++j) {
            bf16_t* dst = &Bs[buf][bhead * 64 + baq * 4 + j][bkq * 4];
            dst[0] = (bf16_t)bvreg[0][j]; dst[1] = (bf16_t)bvreg[1][j];
            dst[2] = (bf16_t)bvreg[2][j]; dst[3] = (bf16_t)bvreg[3][j];
        }
    };

    f32x4 acc[4][2];
#pragma unroll
    for (int mf = 0; mf < 4; ++mf)
#pragma unroll
        for (int nf = 0; nf < 2; ++nf) { f32x4 z = {0,0,0,0}; acc[mf][nf] = z; }

    const int lrow = lane & 15, lkb = (lane >> 4) << 3;
    load_tile(0); store_tile(0); __syncthreads();

    for (int tI = 0; tI < Ktot / FBK; ++tI) {
        const int cur = tI & 1;
        if (tI + 1 < Ktot / FBK) load_tile((tI + 1) * FBK);
#pragma unroll
        for (int kk = 0; kk < 2; ++kk) {
            bf16x8 af[4], bfr[2];
#pragma unroll
            for (int mf = 0; mf < 4; ++mf)
                af[mf] = *(const bf16x8*)&As[cur][wm * 64 + mf * 16 + lrow][kk * 32 + lkb];
#pragma unroll
            for (int nf = 0; nf < 2; ++nf)
                bfr[nf] = *(const bf16x8*)&Bs[cur][wn * 32 + nf * 16 + lrow][kk * 32 + lkb];
#pragma unroll
            for (int mf = 0; mf < 4; ++mf)
#pragma unroll
                for (int nf = 0; nf < 2; ++nf)
                    acc[mf][nf] = __builtin_amdgcn_mfma_f32_16x16x32_bf16(
                        af[mf], bfr[nf], acc[mf][nf], 0, 0, 0);
        }
        if (tI + 1 < Ktot / FBK) store_tile(cur ^ 1);
        __syncthreads();
    }
#pragma unroll
    for (int mf = 0; mf < 4; ++mf) {
        const int row0 = bm + wm * 64 + mf * 16 + ((lane >> 4) << 2);
#pragma unroll
        for (int nf = 0; nf < 2; ++nf) {
            const int col = bn + wn * 32 + nf * 16 + (lane & 15);
#pragma unroll
            for (int i = 0; i < 4; ++i)
                C[(size_t)(row0 + i) * Ntot + col] = acc[mf][nf][i];
        }
    }
}

extern "C" void kernel_launch(void* const* d_in, const int* in_sizes, int n_in,
                              void* d_out, int out_size, void* d_ws, size_t ws_size,
                              hipStream_t stream) {
    (void)in_sizes; (void)n_in; (void)out_size;
    const float* V  = (const float*)d_in[2];   // [B,S,F] = [M][K]
    const float* Vw = (const float*)d_in[5];   // [H,F,A]
    float* out      = (float*)d_out;           // [B,S,H,A] = [M][N]

    const size_t wtBytes = (size_t)Ntot * Ktot * sizeof(bf16_t);   // 2 MiB

    if (ws_size >= wtBytes) {
        bf16_t* Wt = (bf16_t*)d_ws;
        hipLaunchKernelGGL(prepass_w_kernel, dim3(256), dim3(256), 0, stream, Vw, Wt);
        hipLaunchKernelGGL(gemm_fusedA_kernel, dim3((Mtot / 64) * (Ntot / 128)),
                           dim3(256), 0, stream, V, Wt, out);
    } else {
        hipLaunchKernelGGL(vproj_fused_kernel, dim3(256), dim3(512), 0, stream,
                           V, Vw, out);
    }
}

// Round 13
// 27.885 us; speedup vs baseline: 1.0573x; 1.0573x over previous
//
#include <hip/hip_runtime.h>
#include <hip/hip_bf16.h>

typedef __bf16 bf16_t;
typedef __bf16 bf16x4 __attribute__((ext_vector_type(4)));
typedef __bf16 bf16x8 __attribute__((ext_vector_type(8)));
typedef float  f32x4  __attribute__((ext_vector_type(4)));

typedef __attribute__((address_space(1))) const void  gvoid_t;
typedef __attribute__((address_space(3))) void        lvoid_t;

static constexpr int Mtot = 4096;   // B*S
static constexpr int Ntot = 1024;   // H*A
static constexpr int Ktot = 1024;   // F

// out[b,s,h,a] = sum_f value_input[b,s,f] * v_w[h,f,a]
// (reference softmax over q integrates to exactly 1 in the final q-contraction)

// ============================================================================
// Prepass: Ab = bf16(A) [4096][1024]; Wt = bf16 transpose of W: [n=h*64+a][k]
// (R3/R4 proven)
// ============================================================================
__global__ __launch_bounds__(256)
void prepass_kernel(const float* __restrict__ A, const float* __restrict__ W,
                    bf16_t* __restrict__ Ab, bf16_t* __restrict__ Wt)
{
    __shared__ float wtile[64][65];
    const int bid = blockIdx.x, t = threadIdx.x;

    if (bid < 1024) {
        const size_t base = (size_t)bid * 4096 + t * 4;
#pragma unroll
        for (int r = 0; r < 4; ++r) {
            const size_t i = base + (size_t)r * 1024;
            const f32x4 v = *(const f32x4*)(A + i);
            bf16x4 p = {(bf16_t)v[0], (bf16_t)v[1], (bf16_t)v[2], (bf16_t)v[3]};
            *(bf16x4*)(Ab + i) = p;
        }
    } else {
        const int wb = bid - 1024;        // 0..255
        const int head = wb >> 4;
        const int k0 = (wb & 15) * 64;
        const float* wsrc = W + (size_t)head * (Ktot * 64) + (size_t)k0 * 64;
#pragma unroll
        for (int i = 0; i < 4; ++i) {
            const int idx = i * 256 + t;
            const int kr = idx >> 4, a4 = (idx & 15) * 4;
            const f32x4 v = *(const f32x4*)(wsrc + (size_t)kr * 64 + a4);
            wtile[kr][a4 + 0] = v[0]; wtile[kr][a4 + 1] = v[1];
            wtile[kr][a4 + 2] = v[2]; wtile[kr][a4 + 3] = v[3];
        }
        __syncthreads();
#pragma unroll
        for (int i = 0; i < 4; ++i) {
            const int idx = i * 256 + t;
            const int ar = idx >> 4, kc = (idx & 15) * 4;
            bf16x4 p = {(bf16_t)wtile[kc + 0][ar], (bf16_t)wtile[kc + 1][ar],
                        (bf16_t)wtile[kc + 2][ar], (bf16_t)wtile[kc + 3][ar]};
            *(bf16x4*)(Wt + (size_t)(head * 64 + ar) * Ktot + k0 + kc) = p;
        }
    }
}

// ============================================================================
// GEMM: R4's proven kernel (gload_lds staging, XOR swizzle, BM=64 BN=128
// BK=64, 4 waves 2x2, grid 512 = 2 blocks/CU) with ONE change: counted-vmcnt
// two-barrier K-loop (T4, R5's hardware-verified control flow, now
// un-confounded). Per iter: barA -> STAGE(next, 6 loads/wave) -> vmcnt(6)
// (current tile landed; next stays in flight ACROSS both barriers) -> barB
// -> COMPUTE. vmcnt never drains to 0 in steady state.
// ============================================================================
__global__ __launch_bounds__(256, 2)
void gemm_bf16_kernel(const bf16_t* __restrict__ Ab, const bf16_t* __restrict__ Bt,
                      float* __restrict__ C)
{
    __shared__ bf16_t As[2][64 * 64];    // [row][64k], swizzled content
    __shared__ bf16_t Bs[2][128 * 64];

    const int t = threadIdx.x, lane = t & 63, wave = t >> 6;
    const int wm = wave & 1, wn = wave >> 1;

    // XCD swizzle: 512 wgs; XCD x owns 8 M-panels x all 8 N (3MB < 4MB L2)
    const int g = (blockIdx.x & 7) * 64 + (blockIdx.x >> 3);
    const int by = g >> 3, bx = g & 7;
    const int bm = by * 64, bn = bx * 128;

    const int lrow = lane & 15;
    const int lq   = lane >> 4;

    f32x4 acc[2][4];
#pragma unroll
    for (int mf = 0; mf < 2; ++mf)
#pragma unroll
        for (int nf = 0; nf < 4; ++nf) {
            f32x4 z = {0.f, 0.f, 0.f, 0.f};
            acc[mf][nf] = z;
        }

    // 6 gload_lds per thread (2 A + 4 B) per STAGE
    auto STAGE = [&](int buf, int k0) {
#pragma unroll
        for (int j = 0; j < 2; ++j) {
            const int chunk = (wave * 2 + j) * 64 + lane;
            const int row = chunk >> 3;
            const int kb  = ((chunk & 7) ^ (row & 7)) * 8;   // swizzled source col
            const bf16_t* gp = Ab + (size_t)(bm + row) * Ktot + k0 + kb;
            __builtin_amdgcn_global_load_lds((gvoid_t*)gp,
                (lvoid_t*)&As[buf][(wave * 2 + j) * 512], 16, 0, 0);
        }
#pragma unroll
        for (int j = 0; j < 4; ++j) {
            const int chunk = (wave * 4 + j) * 64 + lane;
            const int row = chunk >> 3;
            const int kb  = ((chunk & 7) ^ (row & 7)) * 8;
            const bf16_t* gp = Bt + (size_t)(bn + row) * Ktot + k0 + kb;
            __builtin_amdgcn_global_load_lds((gvoid_t*)gp,
                (lvoid_t*)&Bs[buf][(wave * 4 + j) * 512], 16, 0, 0);
        }
    };

    auto COMPUTE = [&](int cur) {
#pragma unroll
        for (int kk = 0; kk < 2; ++kk) {
            const int c16 = kk * 4 + lq;          // 16B-column 0..7
            bf16x8 af[2], bfr[4];
#pragma unroll
            for (int mf = 0; mf < 2; ++mf) {
                const int R = wm * 32 + mf * 16 + lrow;
                af[mf] = *(const bf16x8*)&As[cur][R * 64 + ((c16 ^ (R & 7)) << 3)];
            }
#pragma unroll
            for (int nf = 0; nf < 4; ++nf) {
                const int R = wn * 64 + nf * 16 + lrow;
                bfr[nf] = *(const bf16x8*)&Bs[cur][R * 64 + ((c16 ^ (R & 7)) << 3)];
            }
            __builtin_amdgcn_s_setprio(1);
#pragma unroll
            for (int mf = 0; mf < 2; ++mf)
#pragma unroll
                for (int nf = 0; nf < 4; ++nf)
                    acc[mf][nf] = __builtin_amdgcn_mfma_f32_16x16x32_bf16(
                        af[mf], bfr[nf], acc[mf][nf], 0, 0, 0);
            __builtin_amdgcn_s_setprio(0);
        }
    };

    constexpr int NT = Ktot / 64;   // 16
    STAGE(0, 0);                    // 6 outstanding

    for (int tI = 0; tI < NT - 1; ++tI) {
        const int cur = tI & 1;
        // barA: all waves done reading buf cur^1 (iter tI-1's COMPUTE)
        __builtin_amdgcn_s_barrier();
        STAGE(cur ^ 1, (tI + 1) * 64);                      // 12 outstanding
        asm volatile("s_waitcnt vmcnt(6)" ::: "memory");    // tile tI landed
        __builtin_amdgcn_sched_barrier(0);
        __builtin_amdgcn_s_barrier();                       // barB: visible to all
        __builtin_amdgcn_sched_barrier(0);
        COMPUTE(cur);
    }
    // tail: tile NT-1
    asm volatile("s_waitcnt vmcnt(0)" ::: "memory");
    __builtin_amdgcn_sched_barrier(0);
    __builtin_amdgcn_s_barrier();
    __builtin_amdgcn_sched_barrier(0);
    COMPUTE((NT - 1) & 1);

    // epilogue: C/D layout col = lane&15, row = (lane>>4)*4 + i
#pragma unroll
    for (int mf = 0; mf < 2; ++mf) {
        const int row0 = bm + wm * 32 + mf * 16 + (lq << 2);
#pragma unroll
        for (int nf = 0; nf < 4; ++nf) {
            const int col = bn + wn * 64 + nf * 16 + lrow;
#pragma unroll
            for (int i = 0; i < 4; ++i)
                C[(size_t)(row0 + i) * Ntot + col] = acc[mf][nf][i];
        }
    }
}

// ============================================================================
// Fallback (ws too small): round-2 fused kernel (proven correct, ~33 us)
// ============================================================================
static constexpr int FBM = 128, FBN = 128, FBK = 64, FBKP = 72;

__global__ __launch_bounds__(512, 2)
void vproj_fused_kernel(const float* __restrict__ A, const float* __restrict__ W,
                        float* __restrict__ C)
{
    __shared__ bf16_t As[2][FBM][FBKP];
    __shared__ bf16_t Bs[2][FBN][FBKP];

    const int t = threadIdx.x, lane = t & 63, wave = t >> 6;
    const int wm = wave >> 2, wn = wave & 3;
    const int tile = (blockIdx.x & 7) * 32 + (blockIdx.x >> 3);
    const int bm = (tile >> 3) * FBM, bn = (tile & 7) * FBN;

    const int bhead = t >> 8, brem = t & 255;
    const int bkq = brem >> 4, baq = brem & 15;
    const float* const wbase = W + ((size_t)((bn >> 6) + bhead)) * (Ktot * 64)
                                 + (size_t)(bkq * 4) * 64 + baq * 4;
    f32x4 avreg[4], bvreg[4];

    auto load_tile = [&](int k0) {
#pragma unroll
        for (int r = 0; r < 4; ++r) {
            const int idx = r * 512 + t;
            avreg[r] = *(const f32x4*)(A + (size_t)(bm + (idx >> 4)) * Ktot + k0 + (idx & 15) * 4);
        }
        const float* wp = wbase + (size_t)k0 * 64;
#pragma unroll
        for (int r = 0; r < 4; ++r) bvreg[r] = *(const f32x4*)(wp + r * 64);
    };
    auto store_tile = [&](int buf) {
#pragma unroll
        for (int r = 0; r < 4; ++r) {
            const int idx = r * 512 + t;
            bf16_t* dst = &As[buf][idx >> 4][(idx & 15) * 4];
            dst[0] = (bf16_t)avreg[r][0]; dst[1] = (bf16_t)avreg[r][1];
            dst[2] = (bf16_t)avreg[r][2]; dst[3] = (bf16_t)avreg[r][3];
        }
#pragma unroll
        for (int j = 0; j < 4; ++j) {
            bf16_t* dst = &Bs[buf][bhead * 64 + baq * 4 + j][bkq * 4];
            dst[0] = (bf16_t)bvreg[0][j]; dst[1] = (bf16_t)bvreg[1][j];
            dst[2] = (bf16_t)bvreg[2][j]; dst[3] = (bf16_t)bvreg[3][j];
        }
    };

    f32x4 acc[4][2];
#pragma unroll
    for (int mf = 0; mf < 4; ++mf)
#pragma unroll
        for (int nf = 0; nf < 2; ++nf) { f32x4 z = {0,0,0,0}; acc[mf][nf] = z; }

    const int lrow = lane & 15, lkb = (lane >> 4) << 3;
    load_tile(0); store_tile(0); __syncthreads();

    for (int tI = 0; tI < Ktot / FBK; ++tI) {
        const int cur = tI & 1;
        if (tI + 1 < Ktot / FBK) load_tile((tI + 1) * FBK);
#pragma unroll
        for (int kk = 0; kk < 2; ++kk) {
            bf16x8 af[4], bfr[2];
#pragma unroll
            for (int mf = 0; mf < 4; ++mf)
                af[mf] = *(const bf16x8*)&As[cur][wm * 64 + mf * 16 + lrow][kk * 32 + lkb];
#pragma unroll
            for (int nf = 0; nf < 2; ++nf)
                bfr[nf] = *(const bf16x8*)&Bs[cur][wn * 32 + nf * 16 + lrow][kk * 32 + lkb];
#pragma unroll
            for (int mf = 0; mf < 4; ++mf)
#pragma unroll
                for (int nf = 0; nf < 2; ++nf)
                    acc[mf][nf] = __builtin_amdgcn_mfma_f32_16x16x32_bf16(
                        af[mf], bfr[nf], acc[mf][nf], 0, 0, 0);
        }
        if (tI + 1 < Ktot / FBK) store_tile(cur ^ 1);
        __syncthreads();
    }
#pragma unroll
    for (int mf = 0; mf < 4; ++mf) {
        const int row0 = bm + wm * 64 + mf * 16 + ((lane >> 4) << 2);
#pragma unroll
        for (int nf = 0; nf < 2; ++nf) {
            const int col = bn + wn * 32 + nf * 16 + (lane & 15);
#pragma unroll
            for (int i = 0; i < 4; ++i)
                C[(size_t)(row0 + i) * Ntot + col] = acc[mf][nf][i];
        }
    }
}

extern "C" void kernel_launch(void* const* d_in, const int* in_sizes, int n_in,
                              void* d_out, int out_size, void* d_ws, size_t ws_size,
                              hipStream_t stream) {
    (void)in_sizes; (void)n_in; (void)out_size;
    const float* V  = (const float*)d_in[2];   // [B,S,F] = [M][K]
    const float* Vw = (const float*)d_in[5];   // [H,F,A]
    float* out      = (float*)d_out;           // [B,S,H,A] = [M][N]

    const size_t abBytes = (size_t)Mtot * Ktot * sizeof(bf16_t);   // 8 MiB
    const size_t wtBytes = (size_t)Ntot * Ktot * sizeof(bf16_t);   // 2 MiB

    if (ws_size >= abBytes + wtBytes) {
        bf16_t* Ab = (bf16_t*)d_ws;
        bf16_t* Wt = (bf16_t*)((char*)d_ws + abBytes);
        hipLaunchKernelGGL(prepass_kernel, dim3(1024 + 256), dim3(256), 0, stream,
                           V, Vw, Ab, Wt);
        hipLaunchKernelGGL(gemm_bf16_kernel, dim3((Mtot / 64) * (Ntot / 128)),
                           dim3(256), 0, stream, Ab, Wt, out);
    } else {
        hipLaunchKernelGGL(vproj_fused_kernel, dim3(256), dim3(512), 0, stream,
                           V, Vw, out);
    }
}